// Round 15
// baseline (227.993 us; speedup 1.0000x reference)
//
#include <hip/hip_runtime.h>
#include <hip/hip_bf16.h>

#define N_TOK 343
#define N_PAD 344
#define BT_J 352                  // bias j-extent (padded: 44 batches of 8)
#define C_DIM 96
#define H_HEADS 24
#define HD 4
#define B_WIN 32
#define LOG2E 1.4426950408889634f
#define SCALE_Q (0.5f * LOG2E)
#define EPS_IN 1e-5f
#define CH_STR (HD * N_PAD)                    // 1376 floats per (b,h)
#define F4_STR (N_PAD)
#define AP ((size_t)B_WIN * H_HEADS * CH_STR)  // 1,056,768 floats per slot
#define BT_ELEMS ((size_t)H_HEADS * BT_J * N_PAD)
#define PS_HALF ((size_t)B_WIN * H_HEADS * N_PAD)
// q/k/v/vf slots: [b][h][n][d] (float4 per token), token row 343 = zero pad
// ws: [0..7AP) q1,k1,q2,k2,v1(->AO),v2,vf | [7AP..) bT | Pa parts | Ps parts

typedef float v2f __attribute__((ext_vector_type(2)));
#define FMA2(a, b, c) __builtin_elementwise_fma(a, b, c)

// ---------------- kernel 1: prep = {QKV GEMM (src-split) | biasT gather} ----------------
__global__ __launch_bounds__(192) void prep_kernel(const float* __restrict__ x1,
                                                   const float* __restrict__ x2,
                                                   const float* __restrict__ w,
                                                   const float* __restrict__ bqkv,
                                                   const float* __restrict__ rpb,
                                                   const int* __restrict__ rel,
                                                   float* __restrict__ ws,
                                                   float* __restrict__ bT) {
    __shared__ float smem[12704];
    const int bid = blockIdx.x, tid = threadIdx.x;
    if (bid < 2112) {
        const int r0t = bid % 11;
        const int rest = bid / 11;
        const int sy = rest % 6, b = rest / 6;
        const int s = sy >> 1, src = sy & 1;
        const int r0 = r0t * 32;
        const int rows = min(32, N_TOK - r0);
        float* xs = smem;                      // [32][97]
        float* wt = smem + 3104;               // [96][100]
        for (int e = tid; e < 96 * 96; e += 192) {
            int j = e / 96, k = e - j * 96;
            wt[k * 100 + j] = w[s * 96 * 96 + e];
        }
        const float* xp = (src == 0 ? x1 : x2) + ((size_t)b * N_TOK + r0) * C_DIM;
        for (int e = tid; e < rows * 96; e += 192) {
            int r = e / 96, k = e - r * 96;
            xs[r * 97 + k] = xp[e];
        }
        __syncthreads();
        const int rg = tid & 7, og = tid >> 3;
        const int oc0 = og * 4, rr = rg * 4;
        float acc[4][4];
        #pragma unroll
        for (int i = 0; i < 4; ++i) {
            float bv = bqkv[s * 96 + oc0 + i];
            #pragma unroll
            for (int j = 0; j < 4; ++j) acc[i][j] = bv;
        }
        for (int k = 0; k < 96; ++k) {
            float4 w4 = *(const float4*)&wt[k * 100 + oc0];
            float wv[4] = {w4.x, w4.y, w4.z, w4.w};
            float xv[4];
            #pragma unroll
            for (int j = 0; j < 4; ++j) xv[j] = xs[(rr + j) * 97 + k];
            #pragma unroll
            for (int i = 0; i < 4; ++i)
                #pragma unroll
                for (int j = 0; j < 4; ++j) acc[i][j] += xv[j] * wv[i];
        }
        const float scl = (s == 0) ? SCALE_Q : 1.0f;
        const int slot = (s == 0) ? (src ? 2 : 0) : (s == 1) ? (src ? 3 : 1) : (src ? 5 : 4);
        #pragma unroll
        for (int j = 0; j < 4; ++j) {
            int row = r0 + rr + j;
            if (row > N_TOK) continue;
            size_t base = (((size_t)b * H_HEADS + og) * N_PAD + row) * 4;
            float4 val = (row == N_TOK)
                ? make_float4(0.f, 0.f, 0.f, 0.f)
                : make_float4(acc[0][j] * scl, acc[1][j] * scl,
                              acc[2][j] * scl, acc[3][j] * scl);
            *(float4*)(ws + (size_t)slot * AP + base) = val;
        }
    } else {
        const int bid2 = bid - 2112;
        const int h = bid2 / 121;
        const int t = bid2 - h * 121;
        const int ti = t / 11, tj = t - ti * 11;
        const int i0 = ti * 32, j0 = tj * 32;
        float* tile = smem;                    // [32][33]
        for (int e = tid; e < 1024; e += 192) {
            int r = e >> 5, c = e & 31;
            int i = i0 + r, j = j0 + c;
            float v = -16384.f;
            if (i < N_TOK && j < N_TOK) v = rpb[rel[i * N_TOK + j] * H_HEADS + h] * LOG2E;
            tile[r * 33 + c] = v;
        }
        __syncthreads();
        for (int e = tid; e < 1024; e += 192) {
            int c = e >> 5, r = e & 31;
            int i = i0 + r, j = j0 + c;
            if (i < N_PAD)
                bT[((size_t)h * BT_J + j) * N_PAD + i] = tile[r * 33 + c];
        }
    }
}

// ---------------- kernel 2: fuse, float4 ----------------
__global__ __launch_bounds__(256) void fuse_kernel(const float* __restrict__ v1,
                                                   const float* __restrict__ v2,
                                                   const float* __restrict__ fw,
                                                   const float* __restrict__ fb,
                                                   float* __restrict__ vf) {
    const int o = blockIdx.x, b = blockIdx.y;
    __shared__ float4 ts4[343];
    __shared__ float red[32];
    __shared__ float fwl[48];
    if (threadIdx.x < 48) fwl[threadIdx.x] = fw[o * 48 + threadIdx.x];
    __syncthreads();
    const float bo = fb[o];
    const float4* p1 = (const float4*)(v1 + (size_t)b * H_HEADS * CH_STR);
    const float4* p2 = (const float4*)(v2 + (size_t)b * H_HEADS * CH_STR);
    float lsum = 0.f, lsq = 0.f;
    for (int e = threadIdx.x; e < 343; e += blockDim.x) {
        float4 acc = make_float4(bo, bo, bo, bo);
        #pragma unroll
        for (int c = 0; c < H_HEADS; ++c) {
            float4 u1 = p1[(size_t)c * F4_STR + e];
            float4 u2 = p2[(size_t)c * F4_STR + e];
            float w1 = fwl[c], w2 = fwl[24 + c];
            acc.x += w1 * u1.x + w2 * u2.x;
            acc.y += w1 * u1.y + w2 * u2.y;
            acc.z += w1 * u1.z + w2 * u2.z;
            acc.w += w1 * u1.w + w2 * u2.w;
        }
        ts4[e] = acc;
        lsum += acc.x + acc.y + acc.z + acc.w;
        lsq += acc.x * acc.x + acc.y * acc.y + acc.z * acc.z + acc.w * acc.w;
    }
    for (int off = 32; off; off >>= 1) {
        lsum += __shfl_xor(lsum, off);
        lsq  += __shfl_xor(lsq, off);
    }
    int wid = threadIdx.x >> 6, lane = threadIdx.x & 63;
    if (lane == 0) { red[wid] = lsum; red[8 + wid] = lsq; }
    __syncthreads();
    if (threadIdx.x == 0) {
        float su = red[0] + red[1] + red[2] + red[3];
        float q  = red[8] + red[9] + red[10] + red[11];
        float mean = su / (float)(N_TOK * HD);
        float var  = q / (float)(N_TOK * HD) - mean * mean;
        red[16] = mean;
        red[17] = rsqrtf(var + EPS_IN);
    }
    __syncthreads();
    const float mean = red[16], inv = red[17];
    float4* outp = (float4*)(vf + ((size_t)b * H_HEADS + o) * CH_STR);
    for (int e = threadIdx.x; e < 343; e += blockDim.x) {
        float4 x = ts4[e];
        float4 r;
        r.x = 1.f / (1.f + __expf(-fmaxf((x.x - mean) * inv, 0.f)));
        r.y = 1.f / (1.f + __expf(-fmaxf((x.y - mean) * inv, 0.f)));
        r.z = 1.f / (1.f + __expf(-fmaxf((x.z - mean) * inv, 0.f)));
        r.w = 1.f / (1.f + __expf(-fmaxf((x.w - mean) * inv, 0.f)));
        outp[e] = r;
    }
}

// ---------------- attention: shared pieces (2 rows/lane, wave-uniform k/v) ----------------
struct JBatch { v2f bv[4]; float4 k1[4], k2[4], vv[4]; };

#define LOAD_BATCH(B_, j0_)                                            \
    _Pragma("unroll")                                                  \
    for (int u = 0; u < 4; ++u) {                                      \
        B_.bv[u] = *(const v2f*)(bP + (size_t)((j0_) + u) * N_PAD);    \
        B_.k1[u] = K1[(j0_) + u];                                      \
        B_.k2[u] = K2[(j0_) + u];                                      \
        B_.vv[u] = Vv[(j0_) + u];                                      \
    }

#define COMP_BATCH(B_)                                                 \
    _Pragma("unroll")                                                  \
    for (int u = 0; u < 4; ++u) {                                      \
        const float4 k1 = B_.k1[u], k2 = B_.k2[u], v = B_.vv[u];       \
        v2f s2 = B_.bv[u];                                             \
        s2 = FMA2((v2f)(k1.x), q1p0, s2); s2 = FMA2((v2f)(k1.y), q1p1, s2); \
        s2 = FMA2((v2f)(k1.z), q1p2, s2); s2 = FMA2((v2f)(k1.w), q1p3, s2); \
        s2 = FMA2((v2f)(k2.x), q2p0, s2); s2 = FMA2((v2f)(k2.y), q2p1, s2); \
        s2 = FMA2((v2f)(k2.z), q2p2, s2); s2 = FMA2((v2f)(k2.w), q2p3, s2); \
        const v2f p2 = {exp2f(s2.x), exp2f(s2.y)};                     \
        sum2 += p2;                                                    \
        a0 = FMA2(p2, (v2f)(v.x), a0); a1 = FMA2(p2, (v2f)(v.y), a1);  \
        a2 = FMA2(p2, (v2f)(v.z), a2); a3 = FMA2(p2, (v2f)(v.w), a3);  \
    }

#define ATTN_SETUP                                                                 \
    const size_t off = ((size_t)b * H_HEADS + h) * CH_STR;                         \
    const float4* __restrict__ K1 = (const float4*)(ws + 1 * AP + off);            \
    const float4* __restrict__ K2 = (const float4*)(ws + 3 * AP + off);            \
    const float4* __restrict__ Vv = (const float4*)(vf + off);                     \
    const float*  __restrict__ Q1 = ws + 0 * AP + off;                             \
    const float*  __restrict__ Q2 = ws + 2 * AP + off;                             \
    const int rA = l * 2, rB = rA + 1;                                             \
    const float4 q1a = *(const float4*)&Q1[rA * 4];                                \
    const float4 q1b = *(const float4*)&Q1[rB * 4];                                \
    const float4 q2a = *(const float4*)&Q2[rA * 4];                                \
    const float4 q2b = *(const float4*)&Q2[rB * 4];                                \
    const v2f q1p0 = {q1a.x, q1b.x}, q1p1 = {q1a.y, q1b.y},                        \
              q1p2 = {q1a.z, q1b.z}, q1p3 = {q1a.w, q1b.w};                        \
    const v2f q2p0 = {q2a.x, q2b.x}, q2p1 = {q2a.y, q2b.y},                        \
              q2p2 = {q2a.z, q2b.z}, q2p3 = {q2a.w, q2b.w};                        \
    v2f sum2 = {0.f, 0.f};                                                         \
    v2f a0 = {0.f, 0.f}, a1 = {0.f, 0.f}, a2 = {0.f, 0.f}, a3 = {0.f, 0.f};

// ---------------- kernel 3a: attention partials, runtime j-split ----------------
__global__ __launch_bounds__(192) void attn_part(const float* __restrict__ ws,
                                                 const float* __restrict__ bT,
                                                 const float* __restrict__ vf,
                                                 float* __restrict__ Pa,
                                                 float* __restrict__ Ps,
                                                 int jspan, int nbatch) {
    const int h = blockIdx.x, b = blockIdx.y, part = blockIdx.z;
    const int l = threadIdx.x;
    if (l >= 172) return;
    ATTN_SETUP
    const int j0h = part * jspan;
    const float* bP = bT + ((size_t)h * BT_J + j0h) * N_PAD + rA;
    K1 += j0h; K2 += j0h; Vv += j0h;           // overreads past 343 are finite; bias kills them
    JBatch A, B;
    LOAD_BATCH(A, 0)
    LOAD_BATCH(B, 4)
    for (int t = 0; t < nbatch; ++t) {
        const int jb = t * 8;
        COMP_BATCH(A)
        if (t < nbatch - 1) { LOAD_BATCH(A, jb + 8) }
        COMP_BATCH(B)
        if (t < nbatch - 1) { LOAD_BATCH(B, jb + 12) }
    }
    float* PaH = Pa + (size_t)part * AP;
    float* PsH = Ps + (size_t)part * PS_HALF;
    const size_t pi = ((size_t)b * H_HEADS + h) * N_PAD;
    *(float4*)(PaH + (pi + rA) * 4) = make_float4(a0.x, a1.x, a2.x, a3.x);
    *(float4*)(PaH + (pi + rB) * 4) = make_float4(a0.y, a1.y, a2.y, a3.y);
    PsH[pi + rA] = sum2.x;
    PsH[pi + rB] = sum2.y;                     // rB==343 lands in pad slot
}

// ---------------- kernel 3b: full-j attention (no-partial fallback) ----------------
__global__ __launch_bounds__(192) void attn_full(const float* __restrict__ ws,
                                                 const float* __restrict__ bT,
                                                 const float* __restrict__ vf,
                                                 float* __restrict__ ao) {
    const int h = blockIdx.x, b = blockIdx.y;
    const int l = threadIdx.x;
    if (l >= 172) return;
    ATTN_SETUP
    const float* bP = bT + (size_t)h * BT_J * N_PAD + rA;
    JBatch A, B;
    LOAD_BATCH(A, 0)
    LOAD_BATCH(B, 4)
    for (int t = 0; t < 43; ++t) {
        const int jb = t * 8;
        COMP_BATCH(A)
        if (t < 42) { LOAD_BATCH(A, jb + 8) }
        COMP_BATCH(B)
        if (t < 42) { LOAD_BATCH(B, jb + 12) }
    }
    {
        const float inv = 1.f / sum2.x;
        float* op = ao + ((size_t)b * N_TOK + rA) * C_DIM + h * HD;
        *(float4*)op = make_float4(a0.x * inv, a1.x * inv, a2.x * inv, a3.x * inv);
    }
    if (rB < N_TOK) {
        const float inv = 1.f / sum2.y;
        float* op = ao + ((size_t)b * N_TOK + rB) * C_DIM + h * HD;
        *(float4*)op = make_float4(a0.y * inv, a1.y * inv, a2.y * inv, a3.y * inv);
    }
}

// ---------------- kernel 3c: gather fallback ----------------
__global__ __launch_bounds__(256) void attn_kernel_g(const float* __restrict__ ws,
                                                     const float* __restrict__ rpb,
                                                     const int* __restrict__ rel,
                                                     const float* __restrict__ vf,
                                                     float* __restrict__ ao) {
    const int h = blockIdx.x, b = blockIdx.y;
    __shared__ float k1s[BT_J * 4], k2s[BT_J * 4], vs[BT_J * 4];
    __shared__ float q1s[N_PAD * 4], q2s[N_PAD * 4];
    const size_t off = ((size_t)b * H_HEADS + h) * CH_STR;
    const float* Q1 = ws + 0 * AP + off;
    const float* K1 = ws + 1 * AP + off;
    const float* Q2 = ws + 2 * AP + off;
    const float* K2 = ws + 3 * AP + off;
    const float* V  = vf + off;
    const int tid = threadIdx.x;
    for (int e = tid; e < N_PAD * 4; e += 256) {
        k1s[e] = K1[e]; k2s[e] = K2[e]; vs[e] = V[e];
        q1s[e] = Q1[e]; q2s[e] = Q2[e];
    }
    for (int e = N_PAD * 4 + tid; e < BT_J * 4; e += 256) {
        k1s[e] = 0.f; k2s[e] = 0.f; vs[e] = 0.f;
    }
    __syncthreads();
    const int wid = tid >> 6, lane = tid & 63;
    const int grp = lane >> 4, l16 = lane & 15;
    const float* rpbh = rpb + h;
    for (int t = 0; t < 22; ++t) {
        const int i = t * 16 + wid * 4 + grp;
        const int ig = min(i, N_TOK - 1);
        const float4 q1 = *(const float4*)&q1s[ig * 4];
        const float4 q2 = *(const float4*)&q2s[ig * 4];
        const int* relRow = rel + (size_t)ig * N_TOK;
        float sum = 0.f, a0 = 0.f, a1 = 0.f, a2 = 0.f, a3 = 0.f;
        #pragma unroll 4
        for (int it = 0; it < 22; ++it) {
            const int jj = it * 16 + l16;
            float s = (jj < N_TOK) ? rpbh[relRow[jj] * H_HEADS] * LOG2E : -16384.f;
            const float4 k1 = *(const float4*)&k1s[jj * 4];
            const float4 k2 = *(const float4*)&k2s[jj * 4];
            s = fmaf(q1.x, k1.x, s); s = fmaf(q1.y, k1.y, s);
            s = fmaf(q1.z, k1.z, s); s = fmaf(q1.w, k1.w, s);
            s = fmaf(q2.x, k2.x, s); s = fmaf(q2.y, k2.y, s);
            s = fmaf(q2.z, k2.z, s); s = fmaf(q2.w, k2.w, s);
            const float p = exp2f(s);
            const float4 v = *(const float4*)&vs[jj * 4];
            sum += p;
            a0 = fmaf(p, v.x, a0); a1 = fmaf(p, v.y, a1);
            a2 = fmaf(p, v.z, a2); a3 = fmaf(p, v.w, a3);
        }
        #pragma unroll
        for (int o = 8; o; o >>= 1) {
            sum += __shfl_xor(sum, o, 16);
            a0 += __shfl_xor(a0, o, 16); a1 += __shfl_xor(a1, o, 16);
            a2 += __shfl_xor(a2, o, 16); a3 += __shfl_xor(a3, o, 16);
        }
        if (l16 == 0 && i < N_TOK) {
            const float inv = 1.f / sum;
            float* op = ao + ((size_t)b * N_TOK + i) * C_DIM + h * HD;
            *(float4*)op = make_float4(a0 * inv, a1 * inv, a2 * inv, a3 * inv);
        }
    }
}

// ---------------- kernel 4: output projection — register-blocked GEMM + partial merge ----------------
__global__ __launch_bounds__(192) void proj_kernel(const float* __restrict__ ao,
                                                   const float* __restrict__ Pa,
                                                   const float* __restrict__ Ps,
                                                   const float* __restrict__ pw,
                                                   const float* __restrict__ pb,
                                                   float* __restrict__ out,
                                                   int split) {
    __shared__ float xs[32 * 97];
    __shared__ float wt[96 * 100];
    __shared__ float sinv[32 * 24];
    const int b = blockIdx.y, row0 = blockIdx.x * 32;
    const int rows = min(32, N_TOK - row0);
    const int tid = threadIdx.x;
    for (int e = tid; e < 96 * 96; e += 192) {
        int c = e / 96, k = e - c * 96;
        wt[k * 100 + c] = pw[e];
    }
    if (split) {
        for (int e = tid; e < rows * 24; e += 192) {
            int r = e / 24, h = e - r * 24;
            size_t pi = ((size_t)b * H_HEADS + h) * N_PAD + row0 + r;
            float s = 0.f;
            for (int p = 0; p < split; ++p) s += Ps[(size_t)p * PS_HALF + pi];
            sinv[r * 24 + h] = 1.f / s;
        }
        __syncthreads();
        for (int e = tid; e < rows * 96; e += 192) {
            int r = e / 96, c = e - r * 96;
            int h = c >> 2, d = c & 3;
            size_t pi = ((size_t)b * H_HEADS + h) * N_PAD + row0 + r;
            float num = 0.f;
            for (int p = 0; p < split; ++p) num += Pa[(size_t)p * AP + pi * 4 + d];
            xs[r * 97 + c] = num * sinv[r * 24 + h];
        }
    } else {
        for (int e = tid; e < rows * 96; e += 192) {
            int r = e / 96, c = e - r * 96;
            xs[r * 97 + c] = ao[((size_t)b * N_TOK + row0) * C_DIM + e];
        }
    }
    __syncthreads();
    const int rg = tid & 7, og = tid >> 3;
    const int oc0 = og * 4, rr = rg * 4;
    float acc[4][4];
    #pragma unroll
    for (int i = 0; i < 4; ++i) {
        float bv = pb[oc0 + i];
        #pragma unroll
        for (int j = 0; j < 4; ++j) acc[i][j] = bv;
    }
    for (int k = 0; k < 96; ++k) {
        float4 w4 = *(const float4*)&wt[k * 100 + oc0];
        float wv[4] = {w4.x, w4.y, w4.z, w4.w};
        float xv[4];
        #pragma unroll
        for (int j = 0; j < 4; ++j) xv[j] = xs[(rr + j) * 97 + k];
        #pragma unroll
        for (int i = 0; i < 4; ++i)
            #pragma unroll
            for (int j = 0; j < 4; ++j) acc[i][j] += xv[j] * wv[i];
    }
    #pragma unroll
    for (int j = 0; j < 4; ++j) {
        int row = row0 + rr + j;
        if (row >= N_TOK) continue;
        *(float4*)(out + ((size_t)b * N_TOK + row) * C_DIM + oc0) =
            make_float4(acc[0][j], acc[1][j], acc[2][j], acc[3][j]);
    }
}

static const void* find_by_size(void* const* d_in, const int* in_sizes, int n_in,
                                int want, int occurrence) {
    int seen = 0;
    for (int i = 0; i < n_in; ++i) {
        if (in_sizes[i] == want) {
            if (seen == occurrence) return d_in[i];
            ++seen;
        }
    }
    return nullptr;
}

extern "C" void kernel_launch(void* const* d_in, const int* in_sizes, int n_in,
                              void* d_out, int out_size, void* d_ws, size_t ws_size,
                              hipStream_t stream) {
    const float* x1     = (const float*)find_by_size(d_in, in_sizes, n_in, 1053696, 0);
    const float* x2     = (const float*)find_by_size(d_in, in_sizes, n_in, 1053696, 1);
    const float* qkv_w  = (const float*)find_by_size(d_in, in_sizes, n_in, 27648, 0);
    const float* qkv_b  = (const float*)find_by_size(d_in, in_sizes, n_in, 288, 0);
    const float* proj_w = (const float*)find_by_size(d_in, in_sizes, n_in, 9216, 0);
    const float* proj_b = (const float*)find_by_size(d_in, in_sizes, n_in, 96, 0);
    const float* rpb    = (const float*)find_by_size(d_in, in_sizes, n_in, 52728, 0);
    const float* fuse_w = (const float*)find_by_size(d_in, in_sizes, n_in, 1152, 0);
    const float* fuse_b = (const float*)find_by_size(d_in, in_sizes, n_in, 24, 0);
    const int*   rel    = (const int*)  find_by_size(d_in, in_sizes, n_in, 117649, 0);

    if (!x1 || !x2 || !qkv_w || !qkv_b || !proj_w || !proj_b || !rpb || !fuse_w ||
        !fuse_b || !rel) {
        x1     = (const float*)d_in[0];
        x2     = (const float*)d_in[1];
        qkv_w  = (const float*)d_in[2];
        qkv_b  = (const float*)d_in[3];
        proj_w = (const float*)d_in[4];
        proj_b = (const float*)d_in[5];
        rpb    = (const float*)d_in[6];
        fuse_w = (const float*)d_in[7];
        fuse_b = (const float*)d_in[8];
        rel    = (const int*)d_in[9];
    }

    float* ws = (float*)d_ws;
    float* V1 = ws + 4 * AP;
    float* V2 = ws + 5 * AP;
    float* VF = ws + 6 * AP;
    float* AO = V1;
    float* BT = ws + 7 * AP;
    float* PA = BT + BT_ELEMS;
    float* PS4 = PA + 4 * AP;
    float* PS2 = PA + 2 * AP;
    float* out = (float*)d_out;

    const bool use_bias = ws_size >= (7 * AP + BT_ELEMS) * sizeof(float);
    const bool split4   = ws_size >= (7 * AP + BT_ELEMS + 4 * AP + 4 * PS_HALF) * sizeof(float);
    const bool split2   = ws_size >= (7 * AP + BT_ELEMS + 2 * AP + 2 * PS_HALF) * sizeof(float);

    prep_kernel<<<use_bias ? 5016 : 2112, 192, 0, stream>>>(x1, x2, qkv_w, qkv_b,
                                                            rpb, rel, ws, BT);
    fuse_kernel<<<dim3(H_HEADS, B_WIN), 256, 0, stream>>>(V1, V2, fuse_w, fuse_b, VF);
    if (use_bias && split4) {
        attn_part<<<dim3(H_HEADS, B_WIN, 4), 192, 0, stream>>>(ws, BT, VF, PA, PS4, 88, 11);
        proj_kernel<<<dim3(11, B_WIN), 192, 0, stream>>>(nullptr, PA, PS4, proj_w, proj_b, out, 4);
    } else if (use_bias && split2) {
        attn_part<<<dim3(H_HEADS, B_WIN, 2), 192, 0, stream>>>(ws, BT, VF, PA, PS2, 176, 22);
        proj_kernel<<<dim3(11, B_WIN), 192, 0, stream>>>(nullptr, PA, PS2, proj_w, proj_b, out, 2);
    } else {
        if (use_bias)
            attn_full<<<dim3(H_HEADS, B_WIN), 192, 0, stream>>>(ws, BT, VF, AO);
        else
            attn_kernel_g<<<dim3(H_HEADS, B_WIN), 256, 0, stream>>>(ws, rpb, rel, VF, AO);
        proj_kernel<<<dim3(11, B_WIN), 192, 0, stream>>>(AO, nullptr, nullptr, proj_w, proj_b, out, 0);
    }
}

// Round 16
// 156.381 us; speedup vs baseline: 1.4579x; 1.4579x over previous
//
#include <hip/hip_runtime.h>
#include <hip/hip_bf16.h>

#define N_TOK 343
#define N_PAD 344
#define BT_J 352                  // bias j-extent (padded: 44 batches of 8)
#define C_DIM 96
#define H_HEADS 24
#define HD 4
#define B_WIN 32
#define LOG2E 1.4426950408889634f
#define SCALE_Q (0.5f * LOG2E)
#define EPS_IN 1e-5f
#define CH_STR (HD * N_PAD)                    // 1376 floats per (b,h)
#define F4_STR (N_PAD)
#define AP ((size_t)B_WIN * H_HEADS * CH_STR)  // 1,056,768 floats per slot
#define BT_ELEMS ((size_t)H_HEADS * BT_J * N_PAD)
#define PS_HALF ((size_t)B_WIN * H_HEADS * N_PAD)
// q/k/v/vf slots: [b][h][n][d] (float4 per token), token row 343 = zero pad
// ws: [0..7AP) q1,k1,q2,k2,v1(->AO),v2,vf | [7AP..) bT | Pa parts | Ps parts

typedef float v2f __attribute__((ext_vector_type(2)));
#define FMA2(a, b, c) __builtin_elementwise_fma(a, b, c)

// ---------------- kernel 1: prep = {QKV GEMM (src-split) | biasT gather} ----------------
__global__ __launch_bounds__(192) void prep_kernel(const float* __restrict__ x1,
                                                   const float* __restrict__ x2,
                                                   const float* __restrict__ w,
                                                   const float* __restrict__ bqkv,
                                                   const float* __restrict__ rpb,
                                                   const int* __restrict__ rel,
                                                   float* __restrict__ ws,
                                                   float* __restrict__ bT) {
    __shared__ float smem[12704];
    const int bid = blockIdx.x, tid = threadIdx.x;
    if (bid < 2112) {
        const int r0t = bid % 11;
        const int rest = bid / 11;
        const int sy = rest % 6, b = rest / 6;
        const int s = sy >> 1, src = sy & 1;
        const int r0 = r0t * 32;
        const int rows = min(32, N_TOK - r0);
        float* xs = smem;                      // [32][97]
        float* wt = smem + 3104;               // [96][100]
        for (int e = tid; e < 96 * 96; e += 192) {
            int j = e / 96, k = e - j * 96;
            wt[k * 100 + j] = w[s * 96 * 96 + e];
        }
        const float* xp = (src == 0 ? x1 : x2) + ((size_t)b * N_TOK + r0) * C_DIM;
        for (int e = tid; e < rows * 96; e += 192) {
            int r = e / 96, k = e - r * 96;
            xs[r * 97 + k] = xp[e];
        }
        __syncthreads();
        const int rg = tid & 7, og = tid >> 3;
        const int oc0 = og * 4, rr = rg * 4;
        float acc[4][4];
        #pragma unroll
        for (int i = 0; i < 4; ++i) {
            float bv = bqkv[s * 96 + oc0 + i];
            #pragma unroll
            for (int j = 0; j < 4; ++j) acc[i][j] = bv;
        }
        for (int k = 0; k < 96; ++k) {
            float4 w4 = *(const float4*)&wt[k * 100 + oc0];
            float wv[4] = {w4.x, w4.y, w4.z, w4.w};
            float xv[4];
            #pragma unroll
            for (int j = 0; j < 4; ++j) xv[j] = xs[(rr + j) * 97 + k];
            #pragma unroll
            for (int i = 0; i < 4; ++i)
                #pragma unroll
                for (int j = 0; j < 4; ++j) acc[i][j] += xv[j] * wv[i];
        }
        const float scl = (s == 0) ? SCALE_Q : 1.0f;
        const int slot = (s == 0) ? (src ? 2 : 0) : (s == 1) ? (src ? 3 : 1) : (src ? 5 : 4);
        #pragma unroll
        for (int j = 0; j < 4; ++j) {
            int row = r0 + rr + j;
            if (row > N_TOK) continue;
            size_t base = (((size_t)b * H_HEADS + og) * N_PAD + row) * 4;
            float4 val = (row == N_TOK)
                ? make_float4(0.f, 0.f, 0.f, 0.f)
                : make_float4(acc[0][j] * scl, acc[1][j] * scl,
                              acc[2][j] * scl, acc[3][j] * scl);
            *(float4*)(ws + (size_t)slot * AP + base) = val;
        }
    } else {
        const int bid2 = bid - 2112;
        const int h = bid2 / 121;
        const int t = bid2 - h * 121;
        const int ti = t / 11, tj = t - ti * 11;
        const int i0 = ti * 32, j0 = tj * 32;
        float* tile = smem;                    // [32][33]
        for (int e = tid; e < 1024; e += 192) {
            int r = e >> 5, c = e & 31;
            int i = i0 + r, j = j0 + c;
            float v = -16384.f;
            if (i < N_TOK && j < N_TOK) v = rpb[rel[i * N_TOK + j] * H_HEADS + h] * LOG2E;
            tile[r * 33 + c] = v;
        }
        __syncthreads();
        for (int e = tid; e < 1024; e += 192) {
            int c = e >> 5, r = e & 31;
            int i = i0 + r, j = j0 + c;
            if (i < N_PAD)
                bT[((size_t)h * BT_J + j) * N_PAD + i] = tile[r * 33 + c];
        }
    }
}

// ---------------- kernel 2: fuse, float4 ----------------
__global__ __launch_bounds__(256) void fuse_kernel(const float* __restrict__ v1,
                                                   const float* __restrict__ v2,
                                                   const float* __restrict__ fw,
                                                   const float* __restrict__ fb,
                                                   float* __restrict__ vf) {
    const int o = blockIdx.x, b = blockIdx.y;
    __shared__ float4 ts4[343];
    __shared__ float red[32];
    __shared__ float fwl[48];
    if (threadIdx.x < 48) fwl[threadIdx.x] = fw[o * 48 + threadIdx.x];
    __syncthreads();
    const float bo = fb[o];
    const float4* p1 = (const float4*)(v1 + (size_t)b * H_HEADS * CH_STR);
    const float4* p2 = (const float4*)(v2 + (size_t)b * H_HEADS * CH_STR);
    float lsum = 0.f, lsq = 0.f;
    for (int e = threadIdx.x; e < 343; e += blockDim.x) {
        float4 acc = make_float4(bo, bo, bo, bo);
        #pragma unroll
        for (int c = 0; c < H_HEADS; ++c) {
            float4 u1 = p1[(size_t)c * F4_STR + e];
            float4 u2 = p2[(size_t)c * F4_STR + e];
            float w1 = fwl[c], w2 = fwl[24 + c];
            acc.x += w1 * u1.x + w2 * u2.x;
            acc.y += w1 * u1.y + w2 * u2.y;
            acc.z += w1 * u1.z + w2 * u2.z;
            acc.w += w1 * u1.w + w2 * u2.w;
        }
        ts4[e] = acc;
        lsum += acc.x + acc.y + acc.z + acc.w;
        lsq += acc.x * acc.x + acc.y * acc.y + acc.z * acc.z + acc.w * acc.w;
    }
    for (int off = 32; off; off >>= 1) {
        lsum += __shfl_xor(lsum, off);
        lsq  += __shfl_xor(lsq, off);
    }
    int wid = threadIdx.x >> 6, lane = threadIdx.x & 63;
    if (lane == 0) { red[wid] = lsum; red[8 + wid] = lsq; }
    __syncthreads();
    if (threadIdx.x == 0) {
        float su = red[0] + red[1] + red[2] + red[3];
        float q  = red[8] + red[9] + red[10] + red[11];
        float mean = su / (float)(N_TOK * HD);
        float var  = q / (float)(N_TOK * HD) - mean * mean;
        red[16] = mean;
        red[17] = rsqrtf(var + EPS_IN);
    }
    __syncthreads();
    const float mean = red[16], inv = red[17];
    float4* outp = (float4*)(vf + ((size_t)b * H_HEADS + o) * CH_STR);
    for (int e = threadIdx.x; e < 343; e += blockDim.x) {
        float4 x = ts4[e];
        float4 r;
        r.x = 1.f / (1.f + __expf(-fmaxf((x.x - mean) * inv, 0.f)));
        r.y = 1.f / (1.f + __expf(-fmaxf((x.y - mean) * inv, 0.f)));
        r.z = 1.f / (1.f + __expf(-fmaxf((x.z - mean) * inv, 0.f)));
        r.w = 1.f / (1.f + __expf(-fmaxf((x.w - mean) * inv, 0.f)));
        outp[e] = r;
    }
}

// ---------------- attention: shared pieces (2 rows/lane, wave-uniform k/v) ----------------
struct JBatch { v2f bv[4]; float4 k1[4], k2[4], vv[4]; };

#define LOAD_BATCH(B_, j0_)                                            \
    _Pragma("unroll")                                                  \
    for (int u = 0; u < 4; ++u) {                                      \
        B_.bv[u] = *(const v2f*)(bP + (size_t)((j0_) + u) * N_PAD);    \
        B_.k1[u] = K1[(j0_) + u];                                      \
        B_.k2[u] = K2[(j0_) + u];                                      \
        B_.vv[u] = Vv[(j0_) + u];                                      \
    }

#define COMP_BATCH(B_)                                                 \
    _Pragma("unroll")                                                  \
    for (int u = 0; u < 4; ++u) {                                      \
        const float4 k1 = B_.k1[u], k2 = B_.k2[u], v = B_.vv[u];       \
        v2f s2 = B_.bv[u];                                             \
        s2 = FMA2((v2f)(k1.x), q1p0, s2); s2 = FMA2((v2f)(k1.y), q1p1, s2); \
        s2 = FMA2((v2f)(k1.z), q1p2, s2); s2 = FMA2((v2f)(k1.w), q1p3, s2); \
        s2 = FMA2((v2f)(k2.x), q2p0, s2); s2 = FMA2((v2f)(k2.y), q2p1, s2); \
        s2 = FMA2((v2f)(k2.z), q2p2, s2); s2 = FMA2((v2f)(k2.w), q2p3, s2); \
        const v2f p2 = {exp2f(s2.x), exp2f(s2.y)};                     \
        sum2 += p2;                                                    \
        a0 = FMA2(p2, (v2f)(v.x), a0); a1 = FMA2(p2, (v2f)(v.y), a1);  \
        a2 = FMA2(p2, (v2f)(v.z), a2); a3 = FMA2(p2, (v2f)(v.w), a3);  \
    }

#define ATTN_SETUP                                                                 \
    const size_t off = ((size_t)b * H_HEADS + h) * CH_STR;                         \
    const float4* __restrict__ K1 = (const float4*)(ws + 1 * AP + off);            \
    const float4* __restrict__ K2 = (const float4*)(ws + 3 * AP + off);            \
    const float4* __restrict__ Vv = (const float4*)(vf + off);                     \
    const float*  __restrict__ Q1 = ws + 0 * AP + off;                             \
    const float*  __restrict__ Q2 = ws + 2 * AP + off;                             \
    const int rA = l * 2, rB = rA + 1;                                             \
    const float4 q1a = *(const float4*)&Q1[rA * 4];                                \
    const float4 q1b = *(const float4*)&Q1[rB * 4];                                \
    const float4 q2a = *(const float4*)&Q2[rA * 4];                                \
    const float4 q2b = *(const float4*)&Q2[rB * 4];                                \
    const v2f q1p0 = {q1a.x, q1b.x}, q1p1 = {q1a.y, q1b.y},                        \
              q1p2 = {q1a.z, q1b.z}, q1p3 = {q1a.w, q1b.w};                        \
    const v2f q2p0 = {q2a.x, q2b.x}, q2p1 = {q2a.y, q2b.y},                        \
              q2p2 = {q2a.z, q2b.z}, q2p3 = {q2a.w, q2b.w};                        \
    v2f sum2 = {0.f, 0.f};                                                         \
    v2f a0 = {0.f, 0.f}, a1 = {0.f, 0.f}, a2 = {0.f, 0.f}, a3 = {0.f, 0.f};

// ---------------- kernel 3a: attention partials, COMPILE-TIME j-split ----------------
// NBATCH batches of 8 j's per part; part j-range = blockIdx.z * NBATCH*8.
template <int NBATCH>
__global__ __launch_bounds__(192) void attn_part_t(const float* __restrict__ ws,
                                                   const float* __restrict__ bT,
                                                   const float* __restrict__ vf,
                                                   float* __restrict__ Pa,
                                                   float* __restrict__ Ps) {
    const int h = blockIdx.x, b = blockIdx.y, part = blockIdx.z;
    const int l = threadIdx.x;
    if (l >= 172) return;
    ATTN_SETUP
    const int j0h = part * (NBATCH * 8);
    const float* bP = bT + ((size_t)h * BT_J + j0h) * N_PAD + rA;
    K1 += j0h; K2 += j0h; Vv += j0h;           // overreads past 343 are finite; bias kills them
    JBatch A, B;
    LOAD_BATCH(A, 0)
    LOAD_BATCH(B, 4)
    #pragma unroll
    for (int t = 0; t < NBATCH; ++t) {
        const int jb = t * 8;
        COMP_BATCH(A)
        if (t < NBATCH - 1) { LOAD_BATCH(A, jb + 8) }
        COMP_BATCH(B)
        if (t < NBATCH - 1) { LOAD_BATCH(B, jb + 12) }
    }
    float* PaH = Pa + (size_t)part * AP;
    float* PsH = Ps + (size_t)part * PS_HALF;
    const size_t pi = ((size_t)b * H_HEADS + h) * N_PAD;
    *(float4*)(PaH + (pi + rA) * 4) = make_float4(a0.x, a1.x, a2.x, a3.x);
    *(float4*)(PaH + (pi + rB) * 4) = make_float4(a0.y, a1.y, a2.y, a3.y);
    PsH[pi + rA] = sum2.x;
    PsH[pi + rB] = sum2.y;                     // rB==343 lands in pad slot
}

// ---------------- kernel 3b: full-j attention (no-partial fallback) ----------------
__global__ __launch_bounds__(192) void attn_full(const float* __restrict__ ws,
                                                 const float* __restrict__ bT,
                                                 const float* __restrict__ vf,
                                                 float* __restrict__ ao) {
    const int h = blockIdx.x, b = blockIdx.y;
    const int l = threadIdx.x;
    if (l >= 172) return;
    ATTN_SETUP
    const float* bP = bT + (size_t)h * BT_J * N_PAD + rA;
    JBatch A, B;
    LOAD_BATCH(A, 0)
    LOAD_BATCH(B, 4)
    #pragma unroll
    for (int t = 0; t < 43; ++t) {
        const int jb = t * 8;
        COMP_BATCH(A)
        if (t < 42) { LOAD_BATCH(A, jb + 8) }
        COMP_BATCH(B)
        if (t < 42) { LOAD_BATCH(B, jb + 12) }
    }
    {
        const float inv = 1.f / sum2.x;
        float* op = ao + ((size_t)b * N_TOK + rA) * C_DIM + h * HD;
        *(float4*)op = make_float4(a0.x * inv, a1.x * inv, a2.x * inv, a3.x * inv);
    }
    if (rB < N_TOK) {
        const float inv = 1.f / sum2.y;
        float* op = ao + ((size_t)b * N_TOK + rB) * C_DIM + h * HD;
        *(float4*)op = make_float4(a0.y * inv, a1.y * inv, a2.y * inv, a3.y * inv);
    }
}

// ---------------- kernel 3c: gather fallback ----------------
__global__ __launch_bounds__(256) void attn_kernel_g(const float* __restrict__ ws,
                                                     const float* __restrict__ rpb,
                                                     const int* __restrict__ rel,
                                                     const float* __restrict__ vf,
                                                     float* __restrict__ ao) {
    const int h = blockIdx.x, b = blockIdx.y;
    __shared__ float k1s[BT_J * 4], k2s[BT_J * 4], vs[BT_J * 4];
    __shared__ float q1s[N_PAD * 4], q2s[N_PAD * 4];
    const size_t off = ((size_t)b * H_HEADS + h) * CH_STR;
    const float* Q1 = ws + 0 * AP + off;
    const float* K1 = ws + 1 * AP + off;
    const float* Q2 = ws + 2 * AP + off;
    const float* K2 = ws + 3 * AP + off;
    const float* V  = vf + off;
    const int tid = threadIdx.x;
    for (int e = tid; e < N_PAD * 4; e += 256) {
        k1s[e] = K1[e]; k2s[e] = K2[e]; vs[e] = V[e];
        q1s[e] = Q1[e]; q2s[e] = Q2[e];
    }
    for (int e = N_PAD * 4 + tid; e < BT_J * 4; e += 256) {
        k1s[e] = 0.f; k2s[e] = 0.f; vs[e] = 0.f;
    }
    __syncthreads();
    const int wid = tid >> 6, lane = tid & 63;
    const int grp = lane >> 4, l16 = lane & 15;
    const float* rpbh = rpb + h;
    for (int t = 0; t < 22; ++t) {
        const int i = t * 16 + wid * 4 + grp;
        const int ig = min(i, N_TOK - 1);
        const float4 q1 = *(const float4*)&q1s[ig * 4];
        const float4 q2 = *(const float4*)&q2s[ig * 4];
        const int* relRow = rel + (size_t)ig * N_TOK;
        float sum = 0.f, a0 = 0.f, a1 = 0.f, a2 = 0.f, a3 = 0.f;
        #pragma unroll 4
        for (int it = 0; it < 22; ++it) {
            const int jj = it * 16 + l16;
            float s = (jj < N_TOK) ? rpbh[relRow[jj] * H_HEADS] * LOG2E : -16384.f;
            const float4 k1 = *(const float4*)&k1s[jj * 4];
            const float4 k2 = *(const float4*)&k2s[jj * 4];
            s = fmaf(q1.x, k1.x, s); s = fmaf(q1.y, k1.y, s);
            s = fmaf(q1.z, k1.z, s); s = fmaf(q1.w, k1.w, s);
            s = fmaf(q2.x, k2.x, s); s = fmaf(q2.y, k2.y, s);
            s = fmaf(q2.z, k2.z, s); s = fmaf(q2.w, k2.w, s);
            const float p = exp2f(s);
            const float4 v = *(const float4*)&vs[jj * 4];
            sum += p;
            a0 = fmaf(p, v.x, a0); a1 = fmaf(p, v.y, a1);
            a2 = fmaf(p, v.z, a2); a3 = fmaf(p, v.w, a3);
        }
        #pragma unroll
        for (int o = 8; o; o >>= 1) {
            sum += __shfl_xor(sum, o, 16);
            a0 += __shfl_xor(a0, o, 16); a1 += __shfl_xor(a1, o, 16);
            a2 += __shfl_xor(a2, o, 16); a3 += __shfl_xor(a3, o, 16);
        }
        if (l16 == 0 && i < N_TOK) {
            const float inv = 1.f / sum;
            float* op = ao + ((size_t)b * N_TOK + i) * C_DIM + h * HD;
            *(float4*)op = make_float4(a0 * inv, a1 * inv, a2 * inv, a3 * inv);
        }
    }
}

// ---------------- kernel 4: output projection — register-blocked GEMM + partial merge ----------------
__global__ __launch_bounds__(192) void proj_kernel(const float* __restrict__ ao,
                                                   const float* __restrict__ Pa,
                                                   const float* __restrict__ Ps,
                                                   const float* __restrict__ pw,
                                                   const float* __restrict__ pb,
                                                   float* __restrict__ out,
                                                   int split) {
    __shared__ float xs[32 * 97];
    __shared__ float wt[96 * 100];
    __shared__ float sinv[32 * 24];
    const int b = blockIdx.y, row0 = blockIdx.x * 32;
    const int rows = min(32, N_TOK - row0);
    const int tid = threadIdx.x;
    for (int e = tid; e < 96 * 96; e += 192) {
        int c = e / 96, k = e - c * 96;
        wt[k * 100 + c] = pw[e];
    }
    if (split) {
        for (int e = tid; e < rows * 24; e += 192) {
            int r = e / 24, h = e - r * 24;
            size_t pi = ((size_t)b * H_HEADS + h) * N_PAD + row0 + r;
            float s = 0.f;
            for (int p = 0; p < split; ++p) s += Ps[(size_t)p * PS_HALF + pi];
            sinv[r * 24 + h] = 1.f / s;
        }
        __syncthreads();
        for (int e = tid; e < rows * 96; e += 192) {
            int r = e / 96, c = e - r * 96;
            int h = c >> 2, d = c & 3;
            size_t pi = ((size_t)b * H_HEADS + h) * N_PAD + row0 + r;
            float num = 0.f;
            for (int p = 0; p < split; ++p) num += Pa[(size_t)p * AP + pi * 4 + d];
            xs[r * 97 + c] = num * sinv[r * 24 + h];
        }
    } else {
        for (int e = tid; e < rows * 96; e += 192) {
            int r = e / 96, c = e - r * 96;
            xs[r * 97 + c] = ao[((size_t)b * N_TOK + row0) * C_DIM + e];
        }
    }
    __syncthreads();
    const int rg = tid & 7, og = tid >> 3;
    const int oc0 = og * 4, rr = rg * 4;
    float acc[4][4];
    #pragma unroll
    for (int i = 0; i < 4; ++i) {
        float bv = pb[oc0 + i];
        #pragma unroll
        for (int j = 0; j < 4; ++j) acc[i][j] = bv;
    }
    for (int k = 0; k < 96; ++k) {
        float4 w4 = *(const float4*)&wt[k * 100 + oc0];
        float wv[4] = {w4.x, w4.y, w4.z, w4.w};
        float xv[4];
        #pragma unroll
        for (int j = 0; j < 4; ++j) xv[j] = xs[(rr + j) * 97 + k];
        #pragma unroll
        for (int i = 0; i < 4; ++i)
            #pragma unroll
            for (int j = 0; j < 4; ++j) acc[i][j] += xv[j] * wv[i];
    }
    #pragma unroll
    for (int j = 0; j < 4; ++j) {
        int row = row0 + rr + j;
        if (row >= N_TOK) continue;
        *(float4*)(out + ((size_t)b * N_TOK + row) * C_DIM + oc0) =
            make_float4(acc[0][j], acc[1][j], acc[2][j], acc[3][j]);
    }
}

static const void* find_by_size(void* const* d_in, const int* in_sizes, int n_in,
                                int want, int occurrence) {
    int seen = 0;
    for (int i = 0; i < n_in; ++i) {
        if (in_sizes[i] == want) {
            if (seen == occurrence) return d_in[i];
            ++seen;
        }
    }
    return nullptr;
}

extern "C" void kernel_launch(void* const* d_in, const int* in_sizes, int n_in,
                              void* d_out, int out_size, void* d_ws, size_t ws_size,
                              hipStream_t stream) {
    const float* x1     = (const float*)find_by_size(d_in, in_sizes, n_in, 1053696, 0);
    const float* x2     = (const float*)find_by_size(d_in, in_sizes, n_in, 1053696, 1);
    const float* qkv_w  = (const float*)find_by_size(d_in, in_sizes, n_in, 27648, 0);
    const float* qkv_b  = (const float*)find_by_size(d_in, in_sizes, n_in, 288, 0);
    const float* proj_w = (const float*)find_by_size(d_in, in_sizes, n_in, 9216, 0);
    const float* proj_b = (const float*)find_by_size(d_in, in_sizes, n_in, 96, 0);
    const float* rpb    = (const float*)find_by_size(d_in, in_sizes, n_in, 52728, 0);
    const float* fuse_w = (const float*)find_by_size(d_in, in_sizes, n_in, 1152, 0);
    const float* fuse_b = (const float*)find_by_size(d_in, in_sizes, n_in, 24, 0);
    const int*   rel    = (const int*)  find_by_size(d_in, in_sizes, n_in, 117649, 0);

    if (!x1 || !x2 || !qkv_w || !qkv_b || !proj_w || !proj_b || !rpb || !fuse_w ||
        !fuse_b || !rel) {
        x1     = (const float*)d_in[0];
        x2     = (const float*)d_in[1];
        qkv_w  = (const float*)d_in[2];
        qkv_b  = (const float*)d_in[3];
        proj_w = (const float*)d_in[4];
        proj_b = (const float*)d_in[5];
        rpb    = (const float*)d_in[6];
        fuse_w = (const float*)d_in[7];
        fuse_b = (const float*)d_in[8];
        rel    = (const int*)d_in[9];
    }

    float* ws = (float*)d_ws;
    float* V1 = ws + 4 * AP;
    float* V2 = ws + 5 * AP;
    float* VF = ws + 6 * AP;
    float* AO = V1;
    float* BT = ws + 7 * AP;
    float* PA = BT + BT_ELEMS;
    float* PS4 = PA + 4 * AP;
    float* PS2 = PA + 2 * AP;
    float* out = (float*)d_out;

    const bool use_bias = ws_size >= (7 * AP + BT_ELEMS) * sizeof(float);
    const bool split4   = ws_size >= (7 * AP + BT_ELEMS + 4 * AP + 4 * PS_HALF) * sizeof(float);
    const bool split2   = ws_size >= (7 * AP + BT_ELEMS + 2 * AP + 2 * PS_HALF) * sizeof(float);

    prep_kernel<<<use_bias ? 5016 : 2112, 192, 0, stream>>>(x1, x2, qkv_w, qkv_b,
                                                            rpb, rel, ws, BT);
    fuse_kernel<<<dim3(H_HEADS, B_WIN), 256, 0, stream>>>(V1, V2, fuse_w, fuse_b, VF);
    if (use_bias && split4) {
        attn_part_t<11><<<dim3(H_HEADS, B_WIN, 4), 192, 0, stream>>>(ws, BT, VF, PA, PS4);
        proj_kernel<<<dim3(11, B_WIN), 192, 0, stream>>>(nullptr, PA, PS4, proj_w, proj_b, out, 4);
    } else if (use_bias && split2) {
        attn_part_t<22><<<dim3(H_HEADS, B_WIN, 2), 192, 0, stream>>>(ws, BT, VF, PA, PS2);
        proj_kernel<<<dim3(11, B_WIN), 192, 0, stream>>>(nullptr, PA, PS2, proj_w, proj_b, out, 2);
    } else {
        if (use_bias)
            attn_full<<<dim3(H_HEADS, B_WIN), 192, 0, stream>>>(ws, BT, VF, AO);
        else
            attn_kernel_g<<<dim3(H_HEADS, B_WIN), 256, 0, stream>>>(ws, rpb, rel, VF, AO);
        proj_kernel<<<dim3(11, B_WIN), 192, 0, stream>>>(AO, nullptr, nullptr, proj_w, proj_b, out, 0);
    }
}